// Round 14
// baseline (154.972 us; speedup 1.0000x reference)
//
#include <hip/hip_runtime.h>
#include <hip/hip_bf16.h>

#define N_NODES 50000
#define N_EDGES 800000
#define D_IN 256
#define D_OUT 96

#define NB 782          // bucket count (dst>>6); also grid of K1/K2
#define BNODES 64       // nodes per bucket
#define CAP 1536        // per-bucket record cap (mean 1024, sigma 32, +16 sigma)
#define EPB 1024        // edges per K1 block (782*1024 >= 800000)
#define EPT 4           // edges per thread (1024/256)
#define WLDS_K 264      // padded k-stride for W in LDS

typedef short bf16x8 __attribute__((ext_vector_type(8)));
typedef float f32x4 __attribute__((ext_vector_type(4)));

static __device__ inline ushort f2bf(float f) {
    union { __hip_bfloat16 h; ushort s; } u;
    u.h = __float2bfloat16(f);
    return u.s;
}
static __device__ inline float bfhi2f(unsigned int hibits) {  // bf16 in top 16 bits
    union { unsigned int u; float f; } v; v.u = hibits; return v.f;
}

// ---------------------------------------------------------------------------
// Kernel 0: wT[c][k] = bf16(W[k][c]) + zero the 782 bucket cursors.
// ---------------------------------------------------------------------------
__global__ __launch_bounds__(256) void gcn_wt_kernel(
    const float* __restrict__ W, ushort* __restrict__ wT,
    int* __restrict__ bucket_cursor) {
    int c = blockIdx.x;    // 0..95
    int k = threadIdx.x;   // 0..255
    wT[c * D_IN + k] = f2bf(W[k * D_OUT + c]);
    int gid = c * 256 + k;
    if (gid < NB) bucket_cursor[gid] = 0;
}

// ---------------------------------------------------------------------------
// Kernel 1: GEMM (64 rows/block, 4 waves, grid 782) + edge-partition tail.
// Phase A: hB[N,96] = bf16(x @ W) via 16x16x32 bf16 MFMA (round-6 core).
// Phase B: partition this block's 1024-edge slice into 782 buckets (dst>>6).
// ---------------------------------------------------------------------------
union GemmSh {
    ushort wlds[96 * WLDS_K];                        // 50688 B
    struct { int lhist[NB]; int lbase[NB]; } p;      //  6256 B
};

__global__ __launch_bounds__(256) void gcn_gemm_part_kernel(
    const float* __restrict__ x, const ushort* __restrict__ wT,
    const int* __restrict__ ei, int* __restrict__ bucket_cursor,
    unsigned int* __restrict__ recs, ushort* __restrict__ hB) {
    __shared__ GemmSh sh;
    const int tid = threadIdx.x;
    const int blk = blockIdx.x;

    // ---- early-issue: this block's partition-tail edges -> registers ----
    const int ebase = blk * EPB;
    const int eend  = min(ebase + EPB, N_EDGES);
    int srcv[EPT], dstv[EPT];
#pragma unroll
    for (int i = 0; i < EPT; ++i) {
        int e = ebase + i * 256 + tid;
        srcv[i] = (e < eend) ? ei[e] : -1;
        dstv[i] = (e < eend) ? ei[N_EDGES + e] : -1;
    }

    // ---- stage wT (96x256 bf16 = 3072 x 16B) -> padded LDS ----
#pragma unroll
    for (int it = 0; it < 12; ++it) {
        int i   = tid + it * 256;
        int c   = i >> 5;
        int k8  = (i & 31) << 3;
        uint4 v = reinterpret_cast<const uint4*>(wT)[i];
        *reinterpret_cast<uint4*>(&sh.wlds[c * WLDS_K + k8]) = v;
    }
    __syncthreads();

    // ---- Phase A: GEMM ----
    {
        const int lane = tid & 63;
        const int wave = tid >> 6;            // 0..3
        const int l15  = lane & 15;
        const int lk   = (lane >> 4) * 8;
        const int arow = blk * 64 + wave * 16 + l15;
        const bool aok = arow < N_NODES;
        const float* xrow = &x[(size_t)(aok ? arow : 0) * D_IN];

        f32x4 acc[6];
#pragma unroll
        for (int c = 0; c < 6; ++c) acc[c] = (f32x4){0.f, 0.f, 0.f, 0.f};

#pragma unroll
        for (int kc = 0; kc < D_IN; kc += 32) {
            float4 v0 = make_float4(0.f, 0.f, 0.f, 0.f);
            float4 v1 = make_float4(0.f, 0.f, 0.f, 0.f);
            if (aok) {
                v0 = *reinterpret_cast<const float4*>(&xrow[kc + lk]);
                v1 = *reinterpret_cast<const float4*>(&xrow[kc + lk + 4]);
            }
            bf16x8 a;
            a[0] = (short)f2bf(v0.x); a[1] = (short)f2bf(v0.y);
            a[2] = (short)f2bf(v0.z); a[3] = (short)f2bf(v0.w);
            a[4] = (short)f2bf(v1.x); a[5] = (short)f2bf(v1.y);
            a[6] = (short)f2bf(v1.z); a[7] = (short)f2bf(v1.w);
#pragma unroll
            for (int c = 0; c < 6; ++c) {
                bf16x8 bf = *reinterpret_cast<const bf16x8*>(
                    &sh.wlds[(c * 16 + l15) * WLDS_K + kc + lk]);
                acc[c] = __builtin_amdgcn_mfma_f32_16x16x32_bf16(a, bf, acc[c], 0, 0, 0);
            }
        }

        const int rbase = blk * 64 + wave * 16 + (lane >> 4) * 4;
#pragma unroll
        for (int r = 0; r < 4; ++r) {
            int orow = rbase + r;
            if (orow < N_NODES) {
#pragma unroll
                for (int c = 0; c < 6; ++c)
                    hB[orow * D_OUT + c * 16 + l15] = f2bf(acc[c][r]);
            }
        }
    }

    // ---- Phase B: partition tail (edges already in registers) ----
    __syncthreads();   // all Wlds reads done; repurpose LDS
    {
        const int t = tid;
        for (int i = t; i < NB; i += 256) sh.p.lhist[i] = 0;
        __syncthreads();

        int bk[EPT]; int rk[EPT]; unsigned int rec[EPT];
#pragma unroll
        for (int i = 0; i < EPT; ++i) {
            bk[i] = -1;
            if ((unsigned)srcv[i] < (unsigned)N_NODES &&
                (unsigned)dstv[i] < (unsigned)N_NODES) {
                bk[i]  = dstv[i] >> 6;
                rec[i] = (unsigned)srcv[i] | ((unsigned)(dstv[i] & 63) << 16);
                rk[i]  = atomicAdd(&sh.p.lhist[bk[i]], 1);
            }
        }
        __syncthreads();
        for (int i = t; i < NB; i += 256)
            sh.p.lbase[i] = atomicAdd(&bucket_cursor[i], sh.p.lhist[i]);
        __syncthreads();
#pragma unroll
        for (int i = 0; i < EPT; ++i) {
            if (bk[i] >= 0) {
                int pos = sh.p.lbase[bk[i]] + rk[i];
                if (pos < CAP)   // 16-sigma headroom; deterministic input
                    recs[bk[i] * CAP + pos] = rec[i];
            }
        }
    }
}

// ---------------------------------------------------------------------------
// Kernel 2: per-bucket LDS CSR + fused aggregation, 64-node buckets.
// 256 thr/block (4 thr/node x 24 feats, 3 x uint4 gathers), x4 edge unroll.
// ~10 KB LDS -> 4+ blocks/CU resident; finer blocks = better dynamic balance.
// ---------------------------------------------------------------------------
__global__ __launch_bounds__(256, 4) void gcn_csr_agg_kernel(
    const ushort* __restrict__ hB, const int* __restrict__ bucket_cursor,
    const unsigned int* __restrict__ recs, const float* __restrict__ bias,
    float* __restrict__ out) {
    __shared__ unsigned int srec[CAP];   // 6144 B
    __shared__ ushort loc[CAP];          // 3072 B
    __shared__ int hist[BNODES];
    __shared__ int scanb[BNODES];
    __shared__ int cur[BNODES];
    const int b = blockIdx.x;
    const int t = threadIdx.x;
    int size = bucket_cursor[b];
    if (size > CAP) size = CAP;

    if (t < BNODES) hist[t] = 0;
    __syncthreads();
    for (int i = t; i < size; i += 256) {
        unsigned int r = recs[b * CAP + i];
        srec[i] = r;
        atomicAdd(&hist[(r >> 16) & 63], 1);
    }
    __syncthreads();
    if (t < BNODES) scanb[t] = hist[t];
    __syncthreads();
    for (int off = 1; off < BNODES; off <<= 1) {
        int u = 0;
        if (t < BNODES && t >= off) u = scanb[t - off];
        __syncthreads();
        if (t < BNODES) scanb[t] += u;
        __syncthreads();
    }
    if (t < BNODES) cur[t] = scanb[t] - hist[t];
    __syncthreads();
    for (int i = t; i < size; i += 256) {
        unsigned int r = srec[i];
        int l = (r >> 16) & 63;
        int p = atomicAdd(&cur[l], 1);
        loc[p] = (ushort)(r & 0xffffu);
    }
    __syncthreads();

    const int nl   = t >> 2;       // 0..63
    const int fs   = t & 3;
    const int node = b * BNODES + nl;
    if (node >= N_NODES) return;

    int deg   = hist[nl];
    int start = cur[nl] - deg;     // cur ended at excl+deg

    float a[24];
#pragma unroll
    for (int j = 0; j < 24; ++j) a[j] = 0.f;

#define ACC8V(v, B)                                \
    a[B+0] += bfhi2f((v).x << 16);                 \
    a[B+1] += bfhi2f((v).x & 0xffff0000u);         \
    a[B+2] += bfhi2f((v).y << 16);                 \
    a[B+3] += bfhi2f((v).y & 0xffff0000u);         \
    a[B+4] += bfhi2f((v).z << 16);                 \
    a[B+5] += bfhi2f((v).z & 0xffff0000u);         \
    a[B+6] += bfhi2f((v).w << 16);                 \
    a[B+7] += bfhi2f((v).w & 0xffff0000u);

    int i = 0;
    for (; i + 4 <= deg; i += 4) {
        int s0 = loc[start + i + 0];
        int s1 = loc[start + i + 1];
        int s2 = loc[start + i + 2];
        int s3 = loc[start + i + 3];
        const ushort* h0 = &hB[s0 * D_OUT + fs * 24];
        const ushort* h1 = &hB[s1 * D_OUT + fs * 24];
        const ushort* h2 = &hB[s2 * D_OUT + fs * 24];
        const ushort* h3 = &hB[s3 * D_OUT + fs * 24];
        uint4 v00 = *reinterpret_cast<const uint4*>(h0 + 0);
        uint4 v01 = *reinterpret_cast<const uint4*>(h0 + 8);
        uint4 v02 = *reinterpret_cast<const uint4*>(h0 + 16);
        uint4 v10 = *reinterpret_cast<const uint4*>(h1 + 0);
        uint4 v11 = *reinterpret_cast<const uint4*>(h1 + 8);
        uint4 v12 = *reinterpret_cast<const uint4*>(h1 + 16);
        uint4 v20 = *reinterpret_cast<const uint4*>(h2 + 0);
        uint4 v21 = *reinterpret_cast<const uint4*>(h2 + 8);
        uint4 v22 = *reinterpret_cast<const uint4*>(h2 + 16);
        uint4 v30 = *reinterpret_cast<const uint4*>(h3 + 0);
        uint4 v31 = *reinterpret_cast<const uint4*>(h3 + 8);
        uint4 v32 = *reinterpret_cast<const uint4*>(h3 + 16);
        ACC8V(v00, 0); ACC8V(v01, 8); ACC8V(v02, 16);
        ACC8V(v10, 0); ACC8V(v11, 8); ACC8V(v12, 16);
        ACC8V(v20, 0); ACC8V(v21, 8); ACC8V(v22, 16);
        ACC8V(v30, 0); ACC8V(v31, 8); ACC8V(v32, 16);
    }
    for (; i < deg; ++i) {
        int s = loc[start + i];
        const ushort* hp = &hB[s * D_OUT + fs * 24];
        uint4 v0 = *reinterpret_cast<const uint4*>(hp + 0);
        uint4 v1 = *reinterpret_cast<const uint4*>(hp + 8);
        uint4 v2 = *reinterpret_cast<const uint4*>(hp + 16);
        ACC8V(v0, 0); ACC8V(v1, 8); ACC8V(v2, 16);
    }
#undef ACC8V

    const float4* bp = reinterpret_cast<const float4*>(&bias[fs * 24]);
    float* op = &out[node * D_OUT + fs * 24];
#pragma unroll
    for (int j = 0; j < 6; ++j) {
        float4 bv = bp[j];
        float4 o  = make_float4(a[j*4+0] + bv.x, a[j*4+1] + bv.y,
                                a[j*4+2] + bv.z, a[j*4+3] + bv.w);
        *reinterpret_cast<float4*>(op + j * 4) = o;
    }
}

// ---------------------------------------------------------------------------
extern "C" void kernel_launch(void* const* d_in, const int* in_sizes, int n_in,
                              void* d_out, int out_size, void* d_ws, size_t ws_size,
                              hipStream_t stream) {
    const float* x  = (const float*)d_in[0];   // [50000, 256] f32
    const int*   ei = (const int*)d_in[1];     // [2, 800000] int32
    const float* W  = (const float*)d_in[2];   // [256, 96] f32
    const float* b  = (const float*)d_in[3];   // [96] f32
    float* out = (float*)d_out;                // [50000, 96] f32

    // workspace layout (bytes, 16B-aligned):
    char* ws = (char*)d_ws;
    ushort*       hB     = (ushort*)(ws);                 //  9,600,000
    ushort*       wT     = (ushort*)(ws + 9600000);       //     49,152
    int*          cursor = (int*)   (ws + 9649152);       //      4,096 (782 used)
    unsigned int* recs   = (unsigned int*)(ws + 9653248); //  4,804,608 (782*1536*4)
    // total 14,457,856 bytes

    // K0: W transpose+bf16, zero bucket cursors
    gcn_wt_kernel<<<dim3(96), 256, 0, stream>>>(W, wT, cursor);

    // K1: GEMM (64 rows/block, grid 782) + edge partition tail
    gcn_gemm_part_kernel<<<dim3(NB), 256, 0, stream>>>(x, wT, ei, cursor, recs, hB);

    // K2: per-bucket LDS CSR + fused aggregation + bias (64-node buckets)
    gcn_csr_agg_kernel<<<dim3(NB), 256, 0, stream>>>(hB, cursor, recs, b, out);
}

// Round 16
// 139.591 us; speedup vs baseline: 1.1102x; 1.1102x over previous
//
#include <hip/hip_runtime.h>
#include <hip/hip_bf16.h>

#define N_NODES 50000
#define N_EDGES 800000
#define D_IN 256
#define D_OUT 96

#define NBLK 391        // bucket count (dst>>7) == grid of gemm+partition & csr_agg
#define NTHR 512
#define CAP  2560       // per-bucket record cap (mean 2046, +11 sigma)
#define EPB  ((N_EDGES + NBLK - 1) / NBLK)   // 2047 edges per block (partition tail)
#define EPT  ((EPB + NTHR - 1) / NTHR)       // 4
#define WLDS_K 264      // padded k-stride for W in LDS

typedef short bf16x8 __attribute__((ext_vector_type(8)));
typedef float f32x4 __attribute__((ext_vector_type(4)));

static __device__ inline ushort f2bf(float f) {
    union { __hip_bfloat16 h; ushort s; } u;
    u.h = __float2bfloat16(f);
    return u.s;
}
static __device__ inline float bfhi2f(unsigned int hibits) {  // bf16 in top 16 bits
    union { unsigned int u; float f; } v; v.u = hibits; return v.f;
}

// ---------------------------------------------------------------------------
// Kernel 0: zero the 391 bucket cursors (ws is re-poisoned 0xAA every launch).
// Completes before K1 via same-stream dispatch ordering.
// ---------------------------------------------------------------------------
__global__ __launch_bounds__(512) void gcn_zero_kernel(int* __restrict__ bucket_cursor) {
    int t = threadIdx.x;
    if (t < NBLK) bucket_cursor[t] = 0;
}

// ---------------------------------------------------------------------------
// Kernel 1: fused GEMM (128 rows/block, 8 waves, grid 391 -> 24 waves/CU) +
// edge-partition tail. Per-block W fp32 -> bf16-transposed LDS staging.
// Partition-tail edge loads issued at kernel entry (hide under MFMA k-loop).
// ---------------------------------------------------------------------------
union GemmSh {
    ushort wlds[96 * WLDS_K];                           // 50688 B
    struct { int lhist[NBLK]; int lbase[NBLK]; } p;     //  3128 B
};

__global__ __launch_bounds__(NTHR) void gcn_gemm_part_kernel(
    const float* __restrict__ x, const float* __restrict__ W,
    const int* __restrict__ ei, int* __restrict__ bucket_cursor,
    unsigned int* __restrict__ recs, ushort* __restrict__ hB) {
    __shared__ GemmSh sh;
    const int tid = threadIdx.x;
    const int blk = blockIdx.x;

    // ---- early-issue: this block's partition-tail edges -> registers ----
    const int ebase = blk * EPB;
    const int eend  = min(ebase + EPB, N_EDGES);
    int srcv[EPT], dstv[EPT];
#pragma unroll
    for (int i = 0; i < EPT; ++i) {
        int e = ebase + i * NTHR + tid;
        srcv[i] = (e < eend) ? ei[e] : -1;
        dstv[i] = (e < eend) ? ei[N_EDGES + e] : -1;
    }

    // ---- stage W fp32 -> bf16 transposed LDS (coalesced f4 reads) ----
    // job j: c4 = j%24 (4 cols), kp = j/24 (k-pair); 3072 jobs = 512 x 6
#pragma unroll
    for (int it = 0; it < 6; ++it) {
        int j  = tid + it * NTHR;
        int c4 = j % 24;
        int kp = j / 24;
        float4 fa = *reinterpret_cast<const float4*>(&W[(kp * 2 + 0) * D_OUT + c4 * 4]);
        float4 fb = *reinterpret_cast<const float4*>(&W[(kp * 2 + 1) * D_OUT + c4 * 4]);
        const float a4[4] = {fa.x, fa.y, fa.z, fa.w};
        const float b4[4] = {fb.x, fb.y, fb.z, fb.w};
#pragma unroll
        for (int jj = 0; jj < 4; ++jj) {
            unsigned int pack = (unsigned int)f2bf(a4[jj]) |
                                ((unsigned int)f2bf(b4[jj]) << 16);
            *reinterpret_cast<unsigned int*>(
                &sh.wlds[(c4 * 4 + jj) * WLDS_K + kp * 2]) = pack;
        }
    }
    __syncthreads();

    // ---- Phase A: GEMM ----
    {
        const int lane = tid & 63;
        const int wave = tid >> 6;            // 0..7
        const int l15  = lane & 15;
        const int lk   = (lane >> 4) * 8;
        const int arow = blk * 128 + wave * 16 + l15;
        const bool aok = arow < N_NODES;
        const float* xrow = &x[(size_t)(aok ? arow : 0) * D_IN];

        f32x4 acc[6];
#pragma unroll
        for (int c = 0; c < 6; ++c) acc[c] = (f32x4){0.f, 0.f, 0.f, 0.f};

#pragma unroll
        for (int kc = 0; kc < D_IN; kc += 32) {
            float4 v0 = make_float4(0.f, 0.f, 0.f, 0.f);
            float4 v1 = make_float4(0.f, 0.f, 0.f, 0.f);
            if (aok) {
                v0 = *reinterpret_cast<const float4*>(&xrow[kc + lk]);
                v1 = *reinterpret_cast<const float4*>(&xrow[kc + lk + 4]);
            }
            bf16x8 a;
            a[0] = (short)f2bf(v0.x); a[1] = (short)f2bf(v0.y);
            a[2] = (short)f2bf(v0.z); a[3] = (short)f2bf(v0.w);
            a[4] = (short)f2bf(v1.x); a[5] = (short)f2bf(v1.y);
            a[6] = (short)f2bf(v1.z); a[7] = (short)f2bf(v1.w);
#pragma unroll
            for (int c = 0; c < 6; ++c) {
                bf16x8 bf = *reinterpret_cast<const bf16x8*>(
                    &sh.wlds[(c * 16 + l15) * WLDS_K + kc + lk]);
                acc[c] = __builtin_amdgcn_mfma_f32_16x16x32_bf16(a, bf, acc[c], 0, 0, 0);
            }
        }

        const int rbase = blk * 128 + wave * 16 + (lane >> 4) * 4;
#pragma unroll
        for (int r = 0; r < 4; ++r) {
            int orow = rbase + r;
            if (orow < N_NODES) {
#pragma unroll
                for (int c = 0; c < 6; ++c)
                    hB[orow * D_OUT + c * 16 + l15] = f2bf(acc[c][r]);
            }
        }
    }

    // ---- Phase B: partition tail (edges already in registers) ----
    __syncthreads();   // all Wlds reads done; repurpose LDS
    {
        const int t = tid;
        for (int i = t; i < NBLK; i += NTHR) sh.p.lhist[i] = 0;
        __syncthreads();

        int bk[EPT]; int rk[EPT]; unsigned int rec[EPT];
#pragma unroll
        for (int i = 0; i < EPT; ++i) {
            bk[i] = -1;
            if ((unsigned)srcv[i] < (unsigned)N_NODES &&
                (unsigned)dstv[i] < (unsigned)N_NODES) {
                bk[i]  = dstv[i] >> 7;
                rec[i] = (unsigned)srcv[i] | ((unsigned)(dstv[i] & 127) << 16);
                rk[i]  = atomicAdd(&sh.p.lhist[bk[i]], 1);
            }
        }
        __syncthreads();
        for (int i = t; i < NBLK; i += NTHR)
            sh.p.lbase[i] = atomicAdd(&bucket_cursor[i], sh.p.lhist[i]);
        __syncthreads();
#pragma unroll
        for (int i = 0; i < EPT; ++i) {
            if (bk[i] >= 0) {
                int pos = sh.p.lbase[bk[i]] + rk[i];
                if (pos < CAP)   // 11-sigma headroom; deterministic input
                    recs[bk[i] * CAP + pos] = rec[i];
            }
        }
    }
}

// ---------------------------------------------------------------------------
// Kernel 2: per-bucket LDS CSR + fused aggregation (proven round-9 core).
// One block per bucket (128 nodes); 4 threads/node x 24 features (3 x uint4);
// degree loop unrolled x4 -> 12 outstanding 16B gathers per thread.
// ---------------------------------------------------------------------------
__global__ __launch_bounds__(NTHR, 4) void gcn_csr_agg_kernel(
    const ushort* __restrict__ hB, const int* __restrict__ bucket_cursor,
    const unsigned int* __restrict__ recs, const float* __restrict__ bias,
    float* __restrict__ out) {
    __shared__ unsigned int srec[CAP];   // 10240 B
    __shared__ ushort loc[CAP];          //  5120 B
    __shared__ int hist[128];
    __shared__ int scanb[128];
    __shared__ int cur[128];
    const int b = blockIdx.x;
    const int t = threadIdx.x;
    int size = bucket_cursor[b];
    if (size > CAP) size = CAP;

    if (t < 128) hist[t] = 0;
    __syncthreads();
    for (int i = t; i < size; i += NTHR) {
        unsigned int r = recs[b * CAP + i];
        srec[i] = r;
        atomicAdd(&hist[(r >> 16) & 127], 1);
    }
    __syncthreads();
    if (t < 128) scanb[t] = hist[t];
    __syncthreads();
    for (int off = 1; off < 128; off <<= 1) {
        int u = 0;
        if (t < 128 && t >= off) u = scanb[t - off];
        __syncthreads();
        if (t < 128) scanb[t] += u;
        __syncthreads();
    }
    if (t < 128) cur[t] = scanb[t] - hist[t];
    __syncthreads();
    for (int i = t; i < size; i += NTHR) {
        unsigned int r = srec[i];
        int l = (r >> 16) & 127;
        int p = atomicAdd(&cur[l], 1);
        loc[p] = (ushort)(r & 0xffffu);
    }
    __syncthreads();

    const int nl   = t >> 2;       // 0..127
    const int fs   = t & 3;
    const int node = b * 128 + nl;
    if (node >= N_NODES) return;

    int deg   = hist[nl];
    int start = cur[nl] - deg;     // cur ended at excl+deg

    float a[24];
#pragma unroll
    for (int j = 0; j < 24; ++j) a[j] = 0.f;

#define ACC8V(v, B)                                \
    a[B+0] += bfhi2f((v).x << 16);                 \
    a[B+1] += bfhi2f((v).x & 0xffff0000u);         \
    a[B+2] += bfhi2f((v).y << 16);                 \
    a[B+3] += bfhi2f((v).y & 0xffff0000u);         \
    a[B+4] += bfhi2f((v).z << 16);                 \
    a[B+5] += bfhi2f((v).z & 0xffff0000u);         \
    a[B+6] += bfhi2f((v).w << 16);                 \
    a[B+7] += bfhi2f((v).w & 0xffff0000u);

    int i = 0;
    for (; i + 4 <= deg; i += 4) {
        int s0 = loc[start + i + 0];
        int s1 = loc[start + i + 1];
        int s2 = loc[start + i + 2];
        int s3 = loc[start + i + 3];
        const ushort* h0 = &hB[s0 * D_OUT + fs * 24];
        const ushort* h1 = &hB[s1 * D_OUT + fs * 24];
        const ushort* h2 = &hB[s2 * D_OUT + fs * 24];
        const ushort* h3 = &hB[s3 * D_OUT + fs * 24];
        uint4 v00 = *reinterpret_cast<const uint4*>(h0 + 0);
        uint4 v01 = *reinterpret_cast<const uint4*>(h0 + 8);
        uint4 v02 = *reinterpret_cast<const uint4*>(h0 + 16);
        uint4 v10 = *reinterpret_cast<const uint4*>(h1 + 0);
        uint4 v11 = *reinterpret_cast<const uint4*>(h1 + 8);
        uint4 v12 = *reinterpret_cast<const uint4*>(h1 + 16);
        uint4 v20 = *reinterpret_cast<const uint4*>(h2 + 0);
        uint4 v21 = *reinterpret_cast<const uint4*>(h2 + 8);
        uint4 v22 = *reinterpret_cast<const uint4*>(h2 + 16);
        uint4 v30 = *reinterpret_cast<const uint4*>(h3 + 0);
        uint4 v31 = *reinterpret_cast<const uint4*>(h3 + 8);
        uint4 v32 = *reinterpret_cast<const uint4*>(h3 + 16);
        ACC8V(v00, 0); ACC8V(v01, 8); ACC8V(v02, 16);
        ACC8V(v10, 0); ACC8V(v11, 8); ACC8V(v12, 16);
        ACC8V(v20, 0); ACC8V(v21, 8); ACC8V(v22, 16);
        ACC8V(v30, 0); ACC8V(v31, 8); ACC8V(v32, 16);
    }
    for (; i < deg; ++i) {
        int s = loc[start + i];
        const ushort* hp = &hB[s * D_OUT + fs * 24];
        uint4 v0 = *reinterpret_cast<const uint4*>(hp + 0);
        uint4 v1 = *reinterpret_cast<const uint4*>(hp + 8);
        uint4 v2 = *reinterpret_cast<const uint4*>(hp + 16);
        ACC8V(v0, 0); ACC8V(v1, 8); ACC8V(v2, 16);
    }
#undef ACC8V

    const float4* bp = reinterpret_cast<const float4*>(&bias[fs * 24]);
    float* op = &out[node * D_OUT + fs * 24];
#pragma unroll
    for (int j = 0; j < 6; ++j) {
        float4 bv = bp[j];
        float4 o  = make_float4(a[j*4+0] + bv.x, a[j*4+1] + bv.y,
                                a[j*4+2] + bv.z, a[j*4+3] + bv.w);
        *reinterpret_cast<float4*>(op + j * 4) = o;
    }
}

// ---------------------------------------------------------------------------
extern "C" void kernel_launch(void* const* d_in, const int* in_sizes, int n_in,
                              void* d_out, int out_size, void* d_ws, size_t ws_size,
                              hipStream_t stream) {
    const float* x  = (const float*)d_in[0];   // [50000, 256] f32
    const int*   ei = (const int*)d_in[1];     // [2, 800000] int32
    const float* W  = (const float*)d_in[2];   // [256, 96] f32
    const float* b  = (const float*)d_in[3];   // [96] f32
    float* out = (float*)d_out;                // [50000, 96] f32

    // workspace layout (bytes, 16B-aligned):
    char* ws = (char*)d_ws;
    ushort*       hB     = (ushort*)(ws);                 //  9,600,000
    int*          cursor = (int*)   (ws + 9600000);       //      2,048 (391 used)
    unsigned int* recs   = (unsigned int*)(ws + 9602048); //  4,003,840 (391*2560*4)
    // total 13,605,888 bytes

    // K0: zero bucket cursors
    gcn_zero_kernel<<<dim3(1), 512, 0, stream>>>(cursor);

    // K1: per-block W staging + GEMM (128 rows/block) + edge partition tail
    gcn_gemm_part_kernel<<<dim3(NBLK), NTHR, 0, stream>>>(x, W, ei, cursor, recs, hB);

    // K2: per-bucket LDS CSR + fused aggregation + bias
    gcn_csr_agg_kernel<<<dim3(NBLK), NTHR, 0, stream>>>(hB, cursor, recs, b, out);
}